// Round 2
// 3854.197 us; speedup vs baseline: 1.3217x; 1.3217x over previous
//
#include <hip/hip_runtime.h>
#include <cstdint>
#include <cstddef>

#define H 1024
#define SEQ 512
#define THREEH 3072
#define VOCABN 32000
#define NBLK 64      // recurrence blocks (block = 16 h-indices)
#define NWORK 192    // worker blocks (LLC warm + projection tiles)
#define HPB 16       // h-indices per rnn block

// h strictly in (-1,1); transport stores h+2 in (1,3). Anything <= 0.5
// (0xAA poison = -3e-13, NaN, zeros) means "not yet written".
#define HBIAS 2.0f
#define HVALID 0.5f

// ---------- 16-lane row reduction: pure VALU DPP, no DS ops ----------
template <int CTRL>
__device__ __forceinline__ float dpp_add(float v) {
    return v + __int_as_float(__builtin_amdgcn_update_dpp(
        0, __float_as_int(v), CTRL, 0xF, 0xF, true));
}
__device__ __forceinline__ float row16_sum(float v) {
    v = dpp_add<0xB1>(v);    // quad_perm [1,0,3,2]  (xor 1)
    v = dpp_add<0x4E>(v);    // quad_perm [2,3,0,1]  (xor 2)
    v = dpp_add<0x124>(v);   // row_ror:4
    v = dpp_add<0x128>(v);   // row_ror:8
    return v;                // all 16 lanes of the row hold the sum
}

// ---------- recurrence path: blocks 0..63 ----------
// Wave w owns h-indices i0+4w..i0+4w+3; 16-lane group g (lane>>4) handles
// index i0+4w+g, lane p (lane&15) covers h-columns [64p,64p+64) for all
// 3 gates. LDS holds the BIASED h (h+2); the -2*rowsum(W) correction is
// folded into the gate biases at weight-load time, so the poll path
// writes raw transport values straight to LDS.
__device__ void rnn_path(int blk, int tid, float* smem,
    const float* __restrict__ eWhh, const float* __restrict__ ebhh,
    const float* __restrict__ dWhh, const float* __restrict__ dbhh,
    const float* __restrict__ gxe, const float* __restrict__ gxd,
    float* __restrict__ enc_t, float* __restrict__ dec_t)
{
    const int wave = tid >> 6;
    const int lane = tid & 63;
    const int g = lane >> 4;       // h-index offset within the wave
    const int p = lane & 15;       // 64-column slice owner
    const int i0 = blk * HPB;
    const int myidx = i0 + 4 * wave + g;

    float* hs0 = smem;             // [H] double-buffered biased-h broadcast
    float* hs1 = smem + H;

    float4 wreg[3][16];            // [gate][k] = W[gate*H+myidx][64p+4*((k+p)&15)..]
    float br, bz, bn;              // biases with -HBIAS*rowsum(W) folded in
    float hown = 0.f;

    auto load_w = [&](const float* __restrict__ W, const float* __restrict__ b) {
        float ws[3];
#pragma unroll
        for (int gate = 0; gate < 3; ++gate) {
            const float* base = W + (size_t)(gate * H + myidx) * H + 64 * p;
            float s = 0.f;
#pragma unroll
            for (int k = 0; k < 16; ++k) {
                float4 w = *(const float4*)(base + 4 * ((k + p) & 15));
                wreg[gate][k] = w;
                s += w.x + w.y + w.z + w.w;
            }
            ws[gate] = s;
        }
        br = b[myidx]         - HBIAS * row16_sum(ws[0]);
        bz = b[H + myidx]     - HBIAS * row16_sum(ws[1]);
        bn = b[2 * H + myidx] - HBIAS * row16_sum(ws[2]);
    };

    load_w(eWhh, ebhh);

    for (int step = 0; step < 2 * SEQ; ++step) {
        const bool dec = step >= SEQ;
        const int t = dec ? step - SEQ : step;
        if (dec && t == 0) load_w(dWhh, dbhh);   // gxd precomputed upstream

        const float* gx = dec ? gxd : gxe;
        float* tb_out = (dec ? dec_t : enc_t) + (size_t)t * H;
        float* hb = (step & 1) ? hs1 : hs0;

        // gx prefetch (plain cached loads, independent of the poll)
        const float* gxp = gx + (size_t)t * THREEH + myidx;
        float gxr = gxp[0];
        float gxz = gxp[H];
        float gxn = gxp[2 * H];

        // every wave polls its OWN quarter of the previous row (1KB each)
        if (step == 0) {
            *(float4*)&hb[wave * 256 + lane * 4] =
                float4{HBIAS, HBIAS, HBIAS, HBIAS};   // biased zero state
        } else {
            const float* tb_prev =
                (step <= SEQ) ? enc_t + (size_t)(step - 1) * H
                              : dec_t + (size_t)(step - SEQ - 1) * H;
            const unsigned long long* src =
                (const unsigned long long*)tb_prev + wave * 128 + lane * 2;
            union { unsigned long long u; float f[2]; } cv[2];
            for (;;) {
                cv[0].u = __hip_atomic_load(src,
                    __ATOMIC_RELAXED, __HIP_MEMORY_SCOPE_AGENT);
                cv[1].u = __hip_atomic_load(src + 1,
                    __ATOMIC_RELAXED, __HIP_MEMORY_SCOPE_AGENT);
                if ((cv[0].f[0] > HVALID) & (cv[0].f[1] > HVALID) &
                    (cv[1].f[0] > HVALID) & (cv[1].f[1] > HVALID)) break;
                __builtin_amdgcn_s_sleep(1);
            }
            *(float4*)&hb[wave * 256 + lane * 4] =
                float4{cv[0].f[0], cv[0].f[1], cv[1].f[0], cv[1].f[1]};
        }
        __syncthreads();   // the ONLY barrier per step

        // dot products over the biased h; rotation keeps register indices
        // compile-time and LDS reads at worst 2-way conflicted (free).
        float a0 = 0.f, a1 = 0.f, a2 = 0.f;
#pragma unroll
        for (int k = 0; k < 16; ++k) {
            float4 h = *(const float4*)&hb[64 * p + 4 * ((k + p) & 15)];
            float4 w0 = wreg[0][k], w1 = wreg[1][k], w2 = wreg[2][k];
            a0 += w0.x * h.x + w0.y * h.y + w0.z * h.z + w0.w * h.w;
            a1 += w1.x * h.x + w1.y * h.y + w1.z * h.z + w1.w * h.w;
            a2 += w2.x * h.x + w2.y * h.y + w2.z * h.z + w2.w * h.w;
        }
        float sr = row16_sum(a0);
        float sz = row16_sum(a1);
        float sn = row16_sum(a2);

        float rg = 1.f / (1.f + expf(-(gxr + sr + br)));
        float zg = 1.f / (1.f + expf(-(gxz + sz + bz)));
        float ng = tanhf(gxn + rg * (sn + bn));
        float hnew = (1.f - zg) * ng + zg * hown;
        hown = hnew;

        if (p == 0)
            __hip_atomic_store(tb_out + myidx, hnew + HBIAS,
                               __ATOMIC_RELAXED, __HIP_MEMORY_SCOPE_AGENT);
    }
}

// ---------- worker GEMM tile (64x64, TK=16) ----------
// MODE 2: A = dec_t[m] - HBIAS  (projection -> logits)
template <int MODE>
__device__ void gemm_tile(const float* __restrict__ Abase,
                          int m0, int n0,
                          const float* __restrict__ W,
                          const float* __restrict__ bias,
                          float* __restrict__ C, int N,
                          float* __restrict__ sA, float* __restrict__ sB)
{
    const int tid = threadIdx.x;
    const int r = tid >> 2;
    const int c = tid & 3;
    const int tx = tid & 15;
    const int ty = tid >> 4;
    const int m = m0 + r;

    const float* Arow = Abase + (size_t)m * H;
    const float* Brow = W + (size_t)(n0 + r) * H;
    const float abias = (MODE == 2) ? HBIAS : 0.f;

    float acc[4][4] = {};
    for (int k0 = 0; k0 < H; k0 += 16) {
        float4 av = *(const float4*)(Arow + k0 + c * 4);
        float4 bv = *(const float4*)(Brow + k0 + c * 4);
        __syncthreads();
        sA[(c * 4 + 0) * 68 + r] = av.x - abias;
        sA[(c * 4 + 1) * 68 + r] = av.y - abias;
        sA[(c * 4 + 2) * 68 + r] = av.z - abias;
        sA[(c * 4 + 3) * 68 + r] = av.w - abias;
        sB[(c * 4 + 0) * 68 + r] = bv.x;
        sB[(c * 4 + 1) * 68 + r] = bv.y;
        sB[(c * 4 + 2) * 68 + r] = bv.z;
        sB[(c * 4 + 3) * 68 + r] = bv.w;
        __syncthreads();
#pragma unroll
        for (int kk = 0; kk < 16; ++kk) {
            float4 a = *(const float4*)&sA[kk * 68 + ty * 4];
            float4 b = *(const float4*)&sB[kk * 68 + tx * 4];
            float avv[4] = {a.x, a.y, a.z, a.w};
            float bvv[4] = {b.x, b.y, b.z, b.w};
#pragma unroll
            for (int i = 0; i < 4; ++i)
#pragma unroll
                for (int jj = 0; jj < 4; ++jj)
                    acc[i][jj] += avv[i] * bvv[jj];
        }
    }
    float4 bq = *(const float4*)(bias + n0 + tx * 4);
    float bb[4] = {bq.x, bq.y, bq.z, bq.w};
#pragma unroll
    for (int i = 0; i < 4; ++i) {
        float4 o;
        o.x = acc[i][0] + bb[0];
        o.y = acc[i][1] + bb[1];
        o.z = acc[i][2] + bb[2];
        o.w = acc[i][3] + bb[3];
        *(float4*)&C[(size_t)(m0 + ty * 4 + i) * N + n0 + tx * 4] = o;
    }
}

// ---------- worker path: blocks 64..255 (pure CONSUMER of the rnn) ----------
// Phase 0: warm proj_W into the 256MB LLC during the idle encoder phase.
// Phase 1: projection tiles, gated per 64-row m-block by polling dec_t's
// last row of the block (data-as-flag, atomics), acquire fence, then
// plain tiled loads. Row t fully valid at the LLC implies all rows < t
// are valid (every writer of row t first observed all of row t-1).
// No rnn->worker dependency exists, so partial residency cannot deadlock:
// late workers simply find their polls already satisfied.
__device__ void worker_path(int wid, int tid, float* smem,
    const float* __restrict__ dec_t,
    const float* __restrict__ pW, const float* __restrict__ pb,
    float* __restrict__ out)
{
    float* sA = smem;
    float* sB = smem + 16 * 68;

    // Phase 0: touch one dword per 128B line of pW (131MB / 49152 threads)
    {
        float acc = 0.f;
        const size_t nlines = (size_t)VOCABN * H / 32;   // 1,024,000
        for (size_t i = (size_t)wid * 256 + tid; i < nlines;
             i += (size_t)NWORK * 256)
            acc += pW[i * 32];
        asm volatile("" :: "v"(acc));   // keep the loads alive (no DCE)
    }

    // Phase 1: logits = (dec_t - HBIAS) @ pW^T + pb   (8 x 500 tiles)
    int cur = -1;
    for (int tt = wid; tt < 8 * 500; tt += NWORK) {
        int mb = tt / 500, nb = tt % 500;
        if (mb != cur) {
            if (tid < 64) {
                const unsigned long long* src =
                    (const unsigned long long*)(dec_t + (size_t)(mb * 64 + 63) * H);
                for (;;) {
                    bool ok = true;
#pragma unroll
                    for (int m = 0; m < 8; ++m) {
                        union { unsigned long long u; float f[2]; } c;
                        c.u = __hip_atomic_load(src + tid + 64 * m,
                            __ATOMIC_RELAXED, __HIP_MEMORY_SCOPE_AGENT);
                        ok &= (c.f[0] > HVALID) & (c.f[1] > HVALID);
                    }
                    if (ok) break;
                    __builtin_amdgcn_s_sleep(64);   // coarse: slack is ~250us
                }
            }
            __syncthreads();
            __builtin_amdgcn_fence(__ATOMIC_ACQUIRE, "agent"); // drop stale L1/L2
            cur = mb;
        }
        gemm_tile<2>(dec_t, mb * 64, nb * 64, pW, pb, out, VOCABN, sA, sB);
    }
}

// ---------- fused persistent kernel: 64 rnn blocks + 192 workers ----------
__global__ __launch_bounds__(256, 1) void fused_rnn(
    const float* __restrict__ eWhh, const float* __restrict__ ebhh,
    const float* __restrict__ dWhh, const float* __restrict__ dbhh,
    const float* __restrict__ gxe, const float* __restrict__ gxd,
    float* __restrict__ enc_t, float* __restrict__ dec_t,
    const float* __restrict__ pW, const float* __restrict__ pb,
    float* __restrict__ out)
{
    __shared__ float smem[2176];   // rnn: hs[2][1024]; worker: sA/sB [16][68]
    const int b = blockIdx.x;
    if (b < NBLK)
        rnn_path(b, threadIdx.x, smem, eWhh, ebhh, dWhh, dbhh,
                 gxe, gxd, enc_t, dec_t);
    else
        worker_path(b - NBLK, threadIdx.x, smem, dec_t, pW, pb, out);
}

// ---------- standalone input-side GEMMs (gxe, gxd) ----------
// mode 0: Arow = Abase[inputs[m]]               (encoder embedding gather)
// mode 1: Arow = Abase[m==0 ? 0 : targets[m-1]] (decoder teacher forcing)
__global__ __launch_bounds__(256, 2) void gemm_nt(
    const float* __restrict__ Abase,
    const int* __restrict__ toks0,
    const int* __restrict__ toks1,
    const int mode,
    const float* __restrict__ W,
    const float* __restrict__ bias,
    float* __restrict__ C, const int N)
{
    constexpr int TM = 64, TN = 64, TK = 16;
    __shared__ float As[TK][TM + 4];
    __shared__ float Bs[TK][TN + 4];
    const int tid = threadIdx.x;
    const int n0 = blockIdx.x * TN;
    const int m0 = blockIdx.y * TM;
    const int r = tid >> 2;
    const int c = tid & 3;
    const int tx = tid & 15;
    const int ty = tid >> 4;

    const int m = m0 + r;
    const float* Arow;
    if (mode == 0) Arow = Abase + (size_t)toks0[m] * H;
    else           Arow = Abase + (size_t)(m == 0 ? 0 : toks1[m - 1]) * H;
    const float* Brow = W + (size_t)(n0 + r) * H;

    float acc[4][4] = {};
    for (int k0 = 0; k0 < H; k0 += TK) {
        float4 av = *(const float4*)(Arow + k0 + c * 4);
        float4 bv = *(const float4*)(Brow + k0 + c * 4);
        __syncthreads();
        As[c * 4 + 0][r] = av.x; As[c * 4 + 1][r] = av.y;
        As[c * 4 + 2][r] = av.z; As[c * 4 + 3][r] = av.w;
        Bs[c * 4 + 0][r] = bv.x; Bs[c * 4 + 1][r] = bv.y;
        Bs[c * 4 + 2][r] = bv.z; Bs[c * 4 + 3][r] = bv.w;
        __syncthreads();
#pragma unroll
        for (int kk = 0; kk < TK; ++kk) {
            float4 a = *(const float4*)&As[kk][ty * 4];
            float4 b = *(const float4*)&Bs[kk][tx * 4];
            float avv[4] = {a.x, a.y, a.z, a.w};
            float bvv[4] = {b.x, b.y, b.z, b.w};
#pragma unroll
            for (int i = 0; i < 4; ++i)
#pragma unroll
                for (int jj = 0; jj < 4; ++jj)
                    acc[i][jj] += avv[i] * bvv[jj];
        }
    }

    float4 bq = *(const float4*)(bias + n0 + tx * 4);
    float bb[4] = {bq.x, bq.y, bq.z, bq.w};
#pragma unroll
    for (int i = 0; i < 4; ++i) {
        float4 o;
        o.x = acc[i][0] + bb[0];
        o.y = acc[i][1] + bb[1];
        o.z = acc[i][2] + bb[2];
        o.w = acc[i][3] + bb[3];
        *(float4*)&C[(size_t)(m0 + ty * 4 + i) * N + n0 + tx * 4] = o;
    }
}

extern "C" void kernel_launch(void* const* d_in, const int* in_sizes, int n_in,
                              void* d_out, int out_size, void* d_ws, size_t ws_size,
                              hipStream_t stream) {
    const int*   inputs  = (const int*)d_in[0];
    const int*   targets = (const int*)d_in[1];
    const float* emb     = (const float*)d_in[2];
    const float* eWih    = (const float*)d_in[3];
    const float* eWhh    = (const float*)d_in[4];
    const float* ebih    = (const float*)d_in[5];
    const float* ebhh    = (const float*)d_in[6];
    const float* dWih    = (const float*)d_in[7];
    const float* dWhh    = (const float*)d_in[8];
    const float* dbih    = (const float*)d_in[9];
    const float* dbhh    = (const float*)d_in[10];
    const float* pW      = (const float*)d_in[11];
    const float* pb      = (const float*)d_in[12];
    float* out = (float*)d_out;

    float* gxe   = (float*)d_ws;                  // [512][3072]
    float* gxd   = gxe + (size_t)SEQ * THREEH;    // [512][3072]
    float* enc_t = gxd + (size_t)SEQ * THREEH;    // [512][1024] biased
    float* dec_t = enc_t + (size_t)SEQ * H;       // [512][1024] biased

    // input-side GEMMs: gx = Wih @ emb[tok] + bih (both upfront, serial)
    gemm_nt<<<dim3(THREEH / 64, SEQ / 64), 256, 0, stream>>>(
        emb, inputs, targets, 0, eWih, ebih, gxe, THREEH);
    gemm_nt<<<dim3(THREEH / 64, SEQ / 64), 256, 0, stream>>>(
        emb, inputs, targets, 1, dWih, dbih, gxd, THREEH);

    // fused: 64 recurrence blocks + 192 projection workers (consumer-only)
    fused_rnn<<<NBLK + NWORK, 256, 0, stream>>>(
        eWhh, ebhh, dWhh, dbhh, gxe, gxd, enc_t, dec_t, pW, pb, out);
}